// Round 1
// baseline (867.516 us; speedup 1.0000x reference)
//
#include <hip/hip_runtime.h>
#include <hip/hip_bf16.h>
#include <math.h>

// Problem constants (from reference):
// logits: (N_LOOPS=4, B=4, L=256, V=50257) f32
// input_ids: (B, L) i32 ; ans_starts: (B,) i32 ; chain_targets: (B, N_LOOPS) i32
// outputs: 3 f32 scalars: avg_loss, avg_acc, final_loop_acc

#define NL 4
#define BB 4
#define LL 256
#define VV 50257
#define VWORDS ((VV + 31) / 32)   // 1571
#define TPB 1024

__global__ __launch_bounds__(TPB) void rowstat_kernel(
    const float* __restrict__ logits,
    const int* __restrict__ input_ids,
    const int* __restrict__ ans_starts,
    const int* __restrict__ chain_targets,
    float* __restrict__ ws)
{
    const int nb = blockIdx.x;        // 0..15
    const int n = nb / BB;
    const int b = nb % BB;
    const int tid = threadIdx.x;

    __shared__ unsigned bitmap[VWORDS];
    __shared__ float sm[TPB];
    __shared__ float ss[TPB];
    __shared__ int   si[TPB];

    // Build per-batch vocab bitmap in LDS
    for (int i = tid; i < VWORDS; i += TPB) bitmap[i] = 0u;
    __syncthreads();
    for (int i = tid; i < LL; i += TPB) {
        int t = input_ids[b * LL + i];
        atomicOr(&bitmap[t >> 5], 1u << (t & 31));
    }
    __syncthreads();

    const int as = ans_starts[b];
    const bool pos_ok = (as >= 1) && (as < LL);
    int as_idx = as - 1;
    if (as_idx < 0) as_idx = 0;
    if (as_idx > LL - 1) as_idx = LL - 1;

    const float* row = logits + (((size_t)n * BB + b) * LL + as_idx) * (size_t)VV;

    // Online masked max / first-argmax / sum-exp
    float m = -INFINITY;
    float s = 0.0f;
    int am = 0x7fffffff;
    for (int v = tid; v < VV; v += TPB) {
        if ((bitmap[v >> 5] >> (v & 31)) & 1u) {
            float x = row[v];
            if (x > m) {
                s = s * expf(m - x) + 1.0f;   // m=-inf => expf(-inf)=0, s*0+1=1
                m = x;
                am = v;
            } else {
                s += expf(x - m);             // x==m => +1, keep earlier index
            }
        }
    }

    sm[tid] = m; ss[tid] = s; si[tid] = am;
    __syncthreads();

    for (int off = TPB / 2; off > 0; off >>= 1) {
        if (tid < off) {
            float m1 = sm[tid],       s1 = ss[tid];       int i1 = si[tid];
            float m2 = sm[tid + off], s2 = ss[tid + off]; int i2 = si[tid + off];
            // argmax: strictly greater wins; ties -> lower index
            int ni = (m2 > m1 || (m2 == m1 && i2 < i1)) ? i2 : i1;
            float nm, ns;
            if (m1 == -INFINITY)      { nm = m2; ns = s2; }
            else if (m2 == -INFINITY) { nm = m1; ns = s1; }
            else {
                nm = fmaxf(m1, m2);
                ns = s1 * expf(m1 - nm) + s2 * expf(m2 - nm);
            }
            sm[tid] = nm; ss[tid] = ns; si[tid] = ni;
        }
        __syncthreads();
    }

    if (tid == 0) {
        const int tgt = chain_targets[b * NL + n];   // chain_targets.T[n][b]
        const bool tgt_ok = ((bitmap[tgt >> 5] >> (tgt & 31)) & 1u) != 0u;
        const bool valid = pos_ok && tgt_ok;
        const float maxv = sm[0];
        const float sumv = ss[0];
        const int pred = si[0];

        float ce = 0.0f, ac = 0.0f, vf = 0.0f;
        if (valid) {
            vf = 1.0f;
            float lt = row[tgt];                     // masked[tgt] == la[tgt] when tgt_ok
            ce = -(lt - maxv - logf(sumv));
            ac = (pred == tgt) ? 1.0f : 0.0f;
        }
        float* w = ws + (size_t)nb * 3;
        w[0] = ce; w[1] = ac; w[2] = vf;
    }
}

__global__ void finalize_kernel(const float* __restrict__ ws, float* __restrict__ out)
{
    if (blockIdx.x == 0 && threadIdx.x == 0) {
        float loss_num = 0.0f, acc_num = 0.0f, has_sum = 0.0f, final_acc = 0.0f;
        for (int n = 0; n < NL; ++n) {
            float ce = 0.0f, ac = 0.0f, cnt = 0.0f;
            for (int b = 0; b < BB; ++b) {
                const float* w = ws + (size_t)(n * BB + b) * 3;
                ce  += w[0];
                ac  += w[1];
                cnt += w[2];
            }
            float denom = fmaxf(cnt, 1.0f);
            float ll = ce / denom;
            float la = ac / denom;
            float has = (cnt > 0.0f) ? 1.0f : 0.0f;
            loss_num += ll * has;
            acc_num  += la * has;
            has_sum  += has;
            if (n == NL - 1) final_acc = la;
        }
        float nv = fmaxf(has_sum, 1.0f);
        out[0] = loss_num / nv;
        out[1] = acc_num / nv;
        out[2] = final_acc;
    }
}

extern "C" void kernel_launch(void* const* d_in, const int* in_sizes, int n_in,
                              void* d_out, int out_size, void* d_ws, size_t ws_size,
                              hipStream_t stream) {
    const float* logits        = (const float*)d_in[0];
    const int*   input_ids     = (const int*)d_in[1];
    const int*   ans_starts    = (const int*)d_in[2];
    const int*   chain_targets = (const int*)d_in[3];
    float* out = (float*)d_out;
    float* ws  = (float*)d_ws;

    rowstat_kernel<<<dim3(NL * BB), dim3(TPB), 0, stream>>>(
        logits, input_ids, ans_starts, chain_targets, ws);
    finalize_kernel<<<dim3(1), dim3(64), 0, stream>>>(ws, out);
}

// Round 2
// 856.431 us; speedup vs baseline: 1.0129x; 1.0129x over previous
//
#include <hip/hip_runtime.h>
#include <hip/hip_bf16.h>
#include <math.h>

// Reference: masked-argmax / masked-log-softmax CE+acc metric.
// logits: (N_LOOPS=4, B=4, L=256, V=50257) f32
// input_ids: (B, L) i32 ; ans_starts: (B,) i32 ; chain_targets: (B, N_LOOPS) i32
// outputs: 3 f32 scalars: avg_loss, avg_acc, final_loop_acc
//
// Structural fact: valid_tok has <=256 set bits per batch (256 input_ids).
// So we compact the unique token ids and only touch those logits (~1 KB/row
// instead of 201 KB/row).

#define NL 4
#define BB 4
#define LL 256
#define VV 50257
#define VWORDS ((VV + 31) / 32)   // 1571
#define TPB 256

__global__ __launch_bounds__(TPB) void rowstat_kernel(
    const float* __restrict__ logits,
    const int* __restrict__ input_ids,
    const int* __restrict__ ans_starts,
    const int* __restrict__ chain_targets,
    float* __restrict__ ws)
{
    const int nb = blockIdx.x;        // 0..15
    const int n = nb / BB;
    const int b = nb % BB;
    const int tid = threadIdx.x;

    __shared__ unsigned bitmap[VWORDS];   // 6284 B
    __shared__ int toks[LL];              // unique token ids (K <= 256)
    __shared__ unsigned ucnt;
    __shared__ float sm[TPB];
    __shared__ float ss[TPB];
    __shared__ int   si[TPB];

    // Zero bitmap + counter
    for (int i = tid; i < VWORDS; i += TPB) bitmap[i] = 0u;
    if (tid == 0) ucnt = 0u;
    __syncthreads();

    // Dedupe-compact: first thread to set a token's bit owns it
    {
        int t = input_ids[b * LL + tid];           // LL == TPB == 256
        unsigned bit = 1u << (t & 31);
        unsigned old = atomicOr(&bitmap[t >> 5], bit);
        if (!(old & bit)) {
            unsigned p = atomicAdd(&ucnt, 1u);
            toks[p] = t;
        }
    }
    __syncthreads();
    const int K = (int)ucnt;                       // >= 1 always

    const int as = ans_starts[b];
    const bool pos_ok = (as >= 1) && (as < LL);
    int as_idx = as - 1;
    if (as_idx < 0) as_idx = 0;
    if (as_idx > LL - 1) as_idx = LL - 1;

    const float* row = logits + (((size_t)n * BB + b) * LL + as_idx) * (size_t)VV;

    // Gather my valid logit
    float x = -INFINITY;
    int   idx = 0x7fffffff;
    if (tid < K) {
        idx = toks[tid];
        x = row[idx];
    }

    // Pass 1: max + first-argmax (lowest token id on ties)
    sm[tid] = x; si[tid] = idx;
    __syncthreads();
    for (int off = TPB / 2; off > 0; off >>= 1) {
        if (tid < off) {
            float m1 = sm[tid], m2 = sm[tid + off];
            int   i1 = si[tid], i2 = si[tid + off];
            if (m2 > m1 || (m2 == m1 && i2 < i1)) { sm[tid] = m2; si[tid] = i2; }
        }
        __syncthreads();
    }
    const float m = sm[0];
    const int pred = si[0];
    __syncthreads();

    // Pass 2: sum of exp(x - m) over valid tokens
    ss[tid] = (tid < K) ? expf(x - m) : 0.0f;
    __syncthreads();
    for (int off = TPB / 2; off > 0; off >>= 1) {
        if (tid < off) ss[tid] += ss[tid + off];
        __syncthreads();
    }

    if (tid == 0) {
        const int tgt = chain_targets[b * NL + n];   // chain_targets.T[n][b]
        const bool tgt_ok = ((bitmap[tgt >> 5] >> (tgt & 31)) & 1u) != 0u;
        const bool valid = pos_ok && tgt_ok;

        float ce = 0.0f, ac = 0.0f, vf = 0.0f;
        if (valid) {
            vf = 1.0f;
            float lt = row[tgt];                     // masked[tgt] == la[tgt] when tgt_ok
            ce = -(lt - m - logf(ss[0]));
            ac = (pred == tgt) ? 1.0f : 0.0f;
        }
        float* w = ws + (size_t)nb * 3;
        w[0] = ce; w[1] = ac; w[2] = vf;
    }
}

__global__ void finalize_kernel(const float* __restrict__ ws, float* __restrict__ out)
{
    if (blockIdx.x == 0 && threadIdx.x == 0) {
        float loss_num = 0.0f, acc_num = 0.0f, has_sum = 0.0f, final_acc = 0.0f;
        for (int n = 0; n < NL; ++n) {
            float ce = 0.0f, ac = 0.0f, cnt = 0.0f;
            for (int b = 0; b < BB; ++b) {
                const float* w = ws + (size_t)(n * BB + b) * 3;
                ce  += w[0];
                ac  += w[1];
                cnt += w[2];
            }
            float denom = fmaxf(cnt, 1.0f);
            float ll = ce / denom;
            float la = ac / denom;
            float has = (cnt > 0.0f) ? 1.0f : 0.0f;
            loss_num += ll * has;
            acc_num  += la * has;
            has_sum  += has;
            if (n == NL - 1) final_acc = la;
        }
        float nv = fmaxf(has_sum, 1.0f);
        out[0] = loss_num / nv;
        out[1] = acc_num / nv;
        out[2] = final_acc;
    }
}

extern "C" void kernel_launch(void* const* d_in, const int* in_sizes, int n_in,
                              void* d_out, int out_size, void* d_ws, size_t ws_size,
                              hipStream_t stream) {
    const float* logits        = (const float*)d_in[0];
    const int*   input_ids     = (const int*)d_in[1];
    const int*   ans_starts    = (const int*)d_in[2];
    const int*   chain_targets = (const int*)d_in[3];
    float* out = (float*)d_out;
    float* ws  = (float*)d_ws;

    rowstat_kernel<<<dim3(NL * BB), dim3(TPB), 0, stream>>>(
        logits, input_ids, ans_starts, chain_targets, ws);
    finalize_kernel<<<dim3(1), dim3(64), 0, stream>>>(ws, out);
}